// Round 11
// baseline (1196.267 us; speedup 1.0000x reference)
//
#include <hip/hip_runtime.h>
#include <hip/hip_bf16.h>
#include <math.h>

typedef __bf16 bf16;
typedef __bf16 bf16x4 __attribute__((ext_vector_type(4)));
typedef __bf16 bf16x8 __attribute__((ext_vector_type(8)));
typedef float f32x4 __attribute__((ext_vector_type(4)));

__device__ __forceinline__ void gld_lds16(const void* g, void* l) {
    __builtin_amdgcn_global_load_lds(
        (const __attribute__((address_space(1))) unsigned int*)g,
        (__attribute__((address_space(3))) unsigned int*)l, 16, 0, 0);
}

#define VMW(n) asm volatile("s_waitcnt vmcnt(" #n ")" ::: "memory")
#define BARR() asm volatile("s_barrier" ::: "memory")

// ---------------- embedding + positional ----------------
__global__ __launch_bounds__(256) void k_embed(const int* __restrict__ tok,
                                               const float* __restrict__ emb,
                                               const float* __restrict__ pos,
                                               float* __restrict__ x) {
    int row = blockIdx.x;
    int l = row & 1023;
    int tk = tok[row];
    const float4* e = (const float4*)(emb + (size_t)tk * 1024);
    const float4* p = (const float4*)(pos + (size_t)l * 1024);
    float4* o = (float4*)(x + (size_t)row * 1024);
    float4 a = e[threadIdx.x], b = p[threadIdx.x];
    o[threadIdx.x] = make_float4(a.x + b.x, a.y + b.y, a.z + b.z, a.w + b.w);
}

// ---------------- layernorm (f32 in, bf16 out) ----------------
__global__ __launch_bounds__(256) void k_ln(const float* __restrict__ x,
                                            const float* __restrict__ g,
                                            const float* __restrict__ b,
                                            bf16* __restrict__ out) {
    int row = blockIdx.x;
    int t = threadIdx.x;
    const float4* xr = (const float4*)(x + (size_t)row * 1024);
    float4 v = xr[t];
    float s1 = v.x + v.y + v.z + v.w;
    float s2 = v.x * v.x + v.y * v.y + v.z * v.z + v.w * v.w;
#pragma unroll
    for (int o = 32; o; o >>= 1) { s1 += __shfl_down(s1, o); s2 += __shfl_down(s2, o); }
    __shared__ float ps1[4], ps2[4], stat[2];
    int lane = t & 63, wid = t >> 6;
    if (lane == 0) { ps1[wid] = s1; ps2[wid] = s2; }
    __syncthreads();
    if (t == 0) {
        float a1 = ps1[0] + ps1[1] + ps1[2] + ps1[3];
        float a2 = ps2[0] + ps2[1] + ps2[2] + ps2[3];
        float mu = a1 * (1.f / 1024.f);
        float var = a2 * (1.f / 1024.f) - mu * mu;
        stat[0] = mu; stat[1] = rsqrtf(var + 1e-5f);
    }
    __syncthreads();
    float mu = stat[0], rs = stat[1];
    const float4* gv = (const float4*)g;
    const float4* bv = (const float4*)b;
    float4 gg = gv[t], bb = bv[t];
    bf16x4 o4;
    o4[0] = (bf16)((v.x - mu) * rs * gg.x + bb.x);
    o4[1] = (bf16)((v.y - mu) * rs * gg.y + bb.y);
    o4[2] = (bf16)((v.z - mu) * rs * gg.z + bb.z);
    o4[3] = (bf16)((v.w - mu) * rs * gg.w + bb.w);
    *(bf16x4*)(out + (size_t)row * 1024 + t * 4) = o4;
}

// ---------------- 64x64 transpose+cast device helper ----------------
__device__ __forceinline__ void transpose64(const float* __restrict__ W,
                                            bf16* __restrict__ WT,
                                            int K, int N, int n0, int k0, int t,
                                            float (*tile)[65]) {
    int tx = t & 15, ty = t >> 4;
#pragma unroll
    for (int i = 0; i < 64; i += 16) {
        float4 v = *(const float4*)&W[(size_t)(k0 + ty + i) * N + n0 + tx * 4];
        tile[ty + i][tx * 4 + 0] = v.x;
        tile[ty + i][tx * 4 + 1] = v.y;
        tile[ty + i][tx * 4 + 2] = v.z;
        tile[ty + i][tx * 4 + 3] = v.w;
    }
    __syncthreads();
    int n = t >> 3, ks = t & 7;
#pragma unroll
    for (int pass = 0; pass < 2; ++pass) {
        int nn = n + pass * 32;
        bf16x8 v;
#pragma unroll
        for (int j = 0; j < 8; ++j) v[j] = (bf16)tile[ks * 8 + j][nn];
        *(bf16x8*)&WT[(size_t)(n0 + nn) * K + k0 + ks * 8] = v;
    }
}

__device__ __forceinline__ void tr_layer_block(int bid,
                                               const float* aw, const float* pw,
                                               const float* m1, const float* m2,
                                               bf16* wT, int t, float (*tile)[65]) {
    const float* src; bf16* dst; int K, N, tn, tk;
    if (bid < 768)       { src = aw; dst = wT;            K = 1024; N = 3072; tn = bid % 48; tk = bid / 48; }
    else if (bid < 1024) { int b = bid - 768;  src = pw; dst = wT + 3145728; K = 1024; N = 1024; tn = b % 16; tk = b / 16; }
    else if (bid < 2048) { int b = bid - 1024; src = m1; dst = wT + 4194304; K = 1024; N = 4096; tn = b % 64; tk = b / 64; }
    else                 { int b = bid - 2048; src = m2; dst = wT + 8388608; K = 4096; N = 1024; tn = b % 16; tk = b / 16; }
    transpose64(src, dst, K, N, tn * 64, tk * 64, t, tile);
}

__global__ __launch_bounds__(256) void k_transpose_layer(const float* __restrict__ aw,
                                                         const float* __restrict__ pw,
                                                         const float* __restrict__ m1,
                                                         const float* __restrict__ m2,
                                                         bf16* __restrict__ wT) {
    __shared__ float tile[64][65];
    tr_layer_block(blockIdx.x, aw, pw, m1, m2, wT, threadIdx.x, tile);
}

// ---------------- 128x128 GEMM, double-buffered 2-phase + T2 swizzle ----------------
// EPI: 0 bias->bf16; 1 resid+bias->f32; 2 resid+gelu->f32; 3 plain f32 (no bias).
// At 2 blocks/CU (64 KB LDS) one block's epilogue overlaps the other's K-loop.
__device__ __forceinline__ void stage128(const char* Ab, const char* Bb,
                                         char* As, char* Bs, int Kb, int k0b, int t) {
#pragma unroll
    for (int j = 0; j < 4; ++j) {
        int idx = j * 256 + t;
        int row = idx >> 3;
        int cb = (idx & 7) << 4;
        int scb = cb ^ ((row & 7) << 4);
        gld_lds16(Ab + (size_t)row * Kb + k0b + scb, As + idx * 16);
        gld_lds16(Bb + (size_t)row * Kb + k0b + scb, Bs + idx * 16);
    }
}

template <int EPI>
__global__ __launch_bounds__(256) void k_gemm2(const bf16* __restrict__ A,
                                               const bf16* __restrict__ BT,
                                               const float* __restrict__ bias,
                                               const float* __restrict__ resid,
                                               float* __restrict__ outf,
                                               bf16* __restrict__ outb,
                                               int N, int K) {
    __shared__ __align__(16) bf16 As[2][128 * 64];
    __shared__ __align__(16) bf16 Bs[2][128 * 64];
    int per = gridDim.x >> 3;
    int tile = (blockIdx.x & 7) * per + (blockIdx.x >> 3);
    int bm = tile & 15, bn = tile >> 4;
    int t = threadIdx.x, lane = t & 63;
    int wr = t >> 7, wc = (t >> 6) & 1;
    f32x4 acc[4][4] = {};
    const char* Ab = (const char*)(A + (size_t)bm * 128 * K);
    const char* Bb = (const char*)(BT + (size_t)bn * 128 * K);
    int Kb = K * 2;
    int nk = K >> 6;
    stage128(Ab, Bb, (char*)As[0], (char*)Bs[0], Kb, 0, t);
    VMW(0); BARR();
    for (int tt = 0; tt < nk; ++tt) {
        int cur = tt & 1;
        if (tt + 1 < nk)
            stage128(Ab, Bb, (char*)As[cur ^ 1], (char*)Bs[cur ^ 1], Kb, (tt + 1) * 128, t);
        const char* Ac = (const char*)As[cur];
        const char* Bc = (const char*)Bs[cur];
#pragma unroll
        for (int kk = 0; kk < 2; ++kk) {
            bf16x8 af[4], bfr[4];
            int cb = kk * 64 + ((lane >> 4) << 4);
#pragma unroll
            for (int m = 0; m < 4; ++m) {
                int r = wr * 64 + m * 16 + (lane & 15);
                af[m] = *(const bf16x8*)(Ac + r * 128 + (cb ^ ((r & 7) << 4)));
            }
#pragma unroll
            for (int n = 0; n < 4; ++n) {
                int r = wc * 64 + n * 16 + (lane & 15);
                bfr[n] = *(const bf16x8*)(Bc + r * 128 + (cb ^ ((r & 7) << 4)));
            }
#pragma unroll
            for (int m = 0; m < 4; ++m)
#pragma unroll
                for (int n = 0; n < 4; ++n)
                    acc[m][n] = __builtin_amdgcn_mfma_f32_16x16x32_bf16(af[m], bfr[n], acc[m][n], 0, 0, 0);
        }
        VMW(0); BARR();
    }
    int row0 = bm * 128 + wr * 64 + ((lane >> 4) << 2);
    int col0 = bn * 128 + wc * 64 + (lane & 15);
#pragma unroll
    for (int m = 0; m < 4; ++m) {
#pragma unroll
        for (int n = 0; n < 4; ++n) {
            int col = col0 + n * 16;
            float bv = (EPI == 3) ? 0.f : bias[col];
#pragma unroll
            for (int r = 0; r < 4; ++r) {
                int row = row0 + m * 16 + r;
                size_t idx = (size_t)row * N + col;
                float v = acc[m][n][r] + bv;
                if (EPI == 0) {
                    outb[idx] = (bf16)v;
                } else if (EPI == 1) {
                    outf[idx] = resid[idx] + v;
                } else if (EPI == 2) {
                    outf[idx] = resid[idx] + 0.5f * v * (1.0f + erff(v * 0.70710678118f));
                } else {
                    outf[idx] = v;
                }
            }
        }
    }
}

// ---------------- 64x64 GEMM (qkv, proj, mlp2) ----------------
// EPI: 0 bias->bf16; 1 resid+bias->f32; 2 resid+gelu->f32 (+opt bf16 dual store)
__device__ __forceinline__ void stage64(const char* Ab, const char* Bb,
                                        char* As, char* Bs, int Kb, int k0b, int t) {
#pragma unroll
    for (int j = 0; j < 2; ++j) {
        int idx = j * 256 + t;
        int row = idx >> 3;
        int cb = (idx & 7) << 4;
        int scb = cb ^ ((row & 7) << 4);
        gld_lds16(Ab + (size_t)row * Kb + k0b + scb, As + idx * 16);
        gld_lds16(Bb + (size_t)row * Kb + k0b + scb, Bs + idx * 16);
    }
}

template <int EPI>
__global__ __launch_bounds__(256) void k_gemm64(const bf16* __restrict__ A,
                                                const bf16* __restrict__ BT,
                                                const float* __restrict__ bias,
                                                const float* __restrict__ resid,
                                                float* __restrict__ outf,
                                                bf16* __restrict__ outb,
                                                int N, int K) {
    __shared__ __align__(16) bf16 As[2][64 * 64];
    __shared__ __align__(16) bf16 Bs[2][64 * 64];
    int per = gridDim.x >> 3;
    int tile = (blockIdx.x & 7) * per + (blockIdx.x >> 3);
    int bm = tile & 31, bn = tile >> 5;
    int t = threadIdx.x, lane = t & 63, wid = t >> 6;
    f32x4 acc[4] = {};
    const char* Ab = (const char*)(A + (size_t)bm * 64 * K);
    const char* Bb = (const char*)(BT + (size_t)bn * 64 * K);
    int Kb = K * 2;
    int nk = K >> 6;
    stage64(Ab, Bb, (char*)As[0], (char*)Bs[0], Kb, 0, t);
    VMW(0); BARR();
    for (int tt = 0; tt < nk; ++tt) {
        int cur = tt & 1;
        if (tt + 1 < nk)
            stage64(Ab, Bb, (char*)As[cur ^ 1], (char*)Bs[cur ^ 1], Kb, (tt + 1) * 128, t);
        const char* Ac = (const char*)As[cur];
        const char* Bc = (const char*)Bs[cur];
#pragma unroll
        for (int kk = 0; kk < 2; ++kk) {
            int cb = kk * 64 + ((lane >> 4) << 4);
            int ra = wid * 16 + (lane & 15);
            bf16x8 af = *(const bf16x8*)(Ac + ra * 128 + (cb ^ ((ra & 7) << 4)));
            bf16x8 bfr[4];
#pragma unroll
            for (int n = 0; n < 4; ++n) {
                int r = n * 16 + (lane & 15);
                bfr[n] = *(const bf16x8*)(Bc + r * 128 + (cb ^ ((r & 7) << 4)));
            }
#pragma unroll
            for (int n = 0; n < 4; ++n)
                acc[n] = __builtin_amdgcn_mfma_f32_16x16x32_bf16(af, bfr[n], acc[n], 0, 0, 0);
        }
        VMW(0); BARR();
    }
    int row0 = bm * 64 + wid * 16 + ((lane >> 4) << 2);
    int col0 = bn * 64 + (lane & 15);
#pragma unroll
    for (int n = 0; n < 4; ++n) {
        int col = col0 + n * 16;
        float bv = bias[col];
#pragma unroll
        for (int r = 0; r < 4; ++r) {
            int row = row0 + r;
            size_t idx = (size_t)row * N + col;
            float v = acc[n][r] + bv;
            if (EPI == 0) {
                outb[idx] = (bf16)v;
            } else {
                float res;
                if (EPI == 1) {
                    res = resid[idx] + v;
                } else {
                    res = resid[idx] + 0.5f * v * (1.0f + erff(v * 0.70710678118f));
                }
                outf[idx] = res;
                if (outb) outb[idx] = (bf16)res;   // fused final cast (layer 5 mlp2)
            }
        }
    }
}

// ---------------- heterogeneous: flash attention + weight transpose ----------------
__global__ __launch_bounds__(256) void k_attn_tr(const bf16* __restrict__ qkv,
                                                 bf16* __restrict__ y,
                                                 const float* __restrict__ aw,
                                                 const float* __restrict__ pw,
                                                 const float* __restrict__ m1,
                                                 const float* __restrict__ m2,
                                                 bf16* __restrict__ wTnext,
                                                 const float* __restrict__ outw,
                                                 bf16* __restrict__ outT) {
    __shared__ __align__(16) char smem[32768];
    int bidg = blockIdx.x;
    int t = threadIdx.x;
    if (bidg >= 512) {
        int tb = bidg - 512;
        float (*tile)[65] = (float(*)[65])smem;
        if (aw) {
            tr_layer_block(tb, aw, pw, m1, m2, wTnext, t, tile);
        } else {
            int tn = tb % 500, tk = tb / 500;
            transpose64(outw, outT, 1024, 32000, tn * 64, tk * 64, t, tile);
        }
        return;
    }
    bf16* Qs = (bf16*)smem;
    bf16* Ks = Qs + 4096;
    bf16* Vt = Ks + 4096;
    bf16* Ps = Vt + 4096;
    int tile = (bidg & 7) * 64 + (bidg >> 3);
    int qb = tile & 15;
    int bh = tile >> 4;
    int b = bh >> 4, h = bh & 15;
    int lane = t & 63, wid = t >> 6;
    int lr = lane & 15, lk = lane >> 4;
    int tok0 = b << 10;
    int q0 = qb << 6;
    const char* qbase = (const char*)qkv;
#pragma unroll
    for (int j = 0; j < 2; ++j) {
        int off = (j * 256 + t) * 16;
        int row = off >> 7, colb = off & 127;
        int scb = colb ^ ((row & 7) << 4);
        gld_lds16(qbase + ((size_t)(tok0 + q0 + row) * 3072 + h * 64) * 2 + scb, (char*)Qs + off);
    }
    VMW(0);
    __syncthreads();
    int qrw = wid * 16 + lr;
    int qsw = (qrw & 7) << 4;
    bf16x8 aq0 = *(const bf16x8*)((const char*)Qs + qrw * 128 + ((lk * 16) ^ qsw));
    bf16x8 aq1 = *(const bf16x8*)((const char*)Qs + qrw * 128 + ((64 + lk * 16) ^ qsw));
    f32x4 o[4] = {};
    float mrun[4], lrun[4];
#pragma unroll
    for (int r = 0; r < 4; ++r) { mrun[r] = -INFINITY; lrun[r] = 0.f; }
    int qrow = q0 + wid * 16 + lk * 4;

    for (int kv0 = 0; kv0 <= q0; kv0 += 64) {
        __syncthreads();
#pragma unroll
        for (int j = 0; j < 2; ++j) {
            int off = (j * 256 + t) * 16;
            int row = off >> 7, colb = off & 127;
            int scb = colb ^ ((row & 7) << 4);
            gld_lds16(qbase + ((size_t)(tok0 + kv0 + row) * 3072 + 1024 + h * 64) * 2 + scb,
                      (char*)Ks + off);
        }
        {
            int kv = t >> 2, d0 = (t & 3) * 16;
            const bf16* vrow = qkv + (size_t)(tok0 + kv0 + kv) * 3072 + 2048 + h * 64 + d0;
#pragma unroll
            for (int e4 = 0; e4 < 4; ++e4) {
                bf16x4 vv = *(const bf16x4*)(vrow + e4 * 4);
#pragma unroll
                for (int i = 0; i < 4; ++i) {
                    int d = d0 + e4 * 4 + i;
                    Vt[d * 64 + (kv ^ ((d & 7) << 3))] = vv[i];
                }
            }
        }
        VMW(0);
        __syncthreads();
        f32x4 s[4];
#pragma unroll
        for (int n = 0; n < 4; ++n) {
            int krw = n * 16 + lr;
            int ksw = (krw & 7) << 4;
            const char* kb = (const char*)Ks + krw * 128;
            bf16x8 bk0 = *(const bf16x8*)(kb + ((lk * 16) ^ ksw));
            bf16x8 bk1 = *(const bf16x8*)(kb + ((64 + lk * 16) ^ ksw));
            f32x4 z = {};
            z = __builtin_amdgcn_mfma_f32_16x16x32_bf16(aq0, bk0, z, 0, 0, 0);
            z = __builtin_amdgcn_mfma_f32_16x16x32_bf16(aq1, bk1, z, 0, 0, 0);
            s[n] = z;
        }
        float mx[4];
#pragma unroll
        for (int r = 0; r < 4; ++r) mx[r] = -INFINITY;
#pragma unroll
        for (int n = 0; n < 4; ++n) {
            int col = kv0 + n * 16 + lr;
#pragma unroll
            for (int r = 0; r < 4; ++r) {
                float sv = s[n][r] * 0.125f;
                sv = (col <= qrow + r) ? sv : -INFINITY;
                s[n][r] = sv;
                mx[r] = fmaxf(mx[r], sv);
            }
        }
#pragma unroll
        for (int r = 0; r < 4; ++r)
#pragma unroll
            for (int m = 1; m < 16; m <<= 1) mx[r] = fmaxf(mx[r], __shfl_xor(mx[r], m));
        float scl[4];
#pragma unroll
        for (int r = 0; r < 4; ++r) {
            float mn = fmaxf(mrun[r], mx[r]);
            scl[r] = __expf(mrun[r] - mn);
            mrun[r] = mn;
        }
        float rs[4] = {0.f, 0.f, 0.f, 0.f};
#pragma unroll
        for (int n = 0; n < 4; ++n)
#pragma unroll
            for (int r = 0; r < 4; ++r) {
                float p = __expf(s[n][r] - mrun[r]);
                s[n][r] = p;
                rs[r] += p;
            }
#pragma unroll
        for (int r = 0; r < 4; ++r) {
#pragma unroll
            for (int m = 1; m < 16; m <<= 1) rs[r] += __shfl_xor(rs[r], m);
            lrun[r] = lrun[r] * scl[r] + rs[r];
        }
#pragma unroll
        for (int n = 0; n < 4; ++n)
#pragma unroll
            for (int r = 0; r < 4; ++r) {
                o[n][r] *= scl[r];
                int prow = lk * 4 + r;
                Ps[wid * 1024 + prow * 64 + ((n * 16 + lr) ^ ((prow & 7) << 3))] = (bf16)s[n][r];
            }
        int psw = (lr & 7) << 3;
        const bf16* pb = Ps + wid * 1024 + lr * 64;
        bf16x8 ap0 = *(const bf16x8*)(pb + ((lk * 8) ^ psw));
        bf16x8 ap1 = *(const bf16x8*)(pb + ((32 + lk * 8) ^ psw));
#pragma unroll
        for (int n = 0; n < 4; ++n) {
            int vrw = n * 16 + lr;
            int vsw = (vrw & 7) << 3;
            const bf16* vb = Vt + vrw * 64;
            bf16x8 bv0 = *(const bf16x8*)(vb + ((lk * 8) ^ vsw));
            bf16x8 bv1 = *(const bf16x8*)(vb + ((32 + lk * 8) ^ vsw));
            o[n] = __builtin_amdgcn_mfma_f32_16x16x32_bf16(ap0, bv0, o[n], 0, 0, 0);
            o[n] = __builtin_amdgcn_mfma_f32_16x16x32_bf16(ap1, bv1, o[n], 0, 0, 0);
        }
    }
#pragma unroll
    for (int n = 0; n < 4; ++n)
#pragma unroll
        for (int r = 0; r < 4; ++r) {
            int row = tok0 + qrow + r;
            y[(size_t)row * 1024 + h * 64 + n * 16 + lr] = (bf16)(o[n][r] / lrun[r]);
        }
}

extern "C" void kernel_launch(void* const* d_in, const int* in_sizes, int n_in,
                              void* d_out, int out_size, void* d_ws, size_t ws_size,
                              hipStream_t stream) {
    const int*   tokens = (const int*)d_in[0];
    const float* pos    = (const float*)d_in[1];
    const float* emb    = (const float*)d_in[2];
    const float* ln1_g  = (const float*)d_in[3];
    const float* ln1_b  = (const float*)d_in[4];
    const float* ln2_g  = (const float*)d_in[5];
    const float* ln2_b  = (const float*)d_in[6];
    const float* attn_w = (const float*)d_in[7];
    const float* attn_b = (const float*)d_in[8];
    const float* proj_w = (const float*)d_in[9];
    const float* proj_b = (const float*)d_in[10];
    const float* mlp_w1 = (const float*)d_in[11];
    const float* mlp_b1 = (const float*)d_in[12];
    const float* mlp_w2 = (const float*)d_in[13];
    const float* mlp_b2 = (const float*)d_in[14];
    const float* out_w  = (const float*)d_in[15];
    float* out = (float*)d_out;

    char* ws = (char*)d_ws;
    size_t off = 0;
    auto alloc = [&](size_t bytes) {
        void* p = ws + off;
        off = (off + bytes + 255) & ~(size_t)255;
        return p;
    };
    float* x   = (float*)alloc((size_t)2048 * 1024 * 4);
    bf16* hb   = (bf16*)alloc((size_t)2048 * 1024 * 2);
    bf16* qkvb = (bf16*)alloc((size_t)2048 * 3072 * 2);
    bf16* yb   = (bf16*)alloc((size_t)2048 * 1024 * 2);
    bf16* hidb = (bf16*)alloc((size_t)2048 * 4096 * 2);
    // outT (32000x1024) doubles as wT slot0 in its first 9437184 elements:
    // slot0's last read (layer-4 mlp2) precedes outT's write (layer-5 attn launch).
    bf16* outT = (bf16*)alloc((size_t)32000 * 1024 * 2);
    bf16* slot1 = (bf16*)alloc((size_t)9437184 * 2);
    bf16* slots[2] = { outT, slot1 };

    k_embed<<<2048, 256, 0, stream>>>(tokens, emb, pos, x);
    k_transpose_layer<<<3072, 256, 0, stream>>>(attn_w, proj_w, mlp_w1, mlp_w2, slots[0]);

    for (int i = 0; i < 6; ++i) {
        bf16* wT = slots[i & 1];
        k_ln<<<2048, 256, 0, stream>>>(x, ln1_g + i * 1024, ln1_b + i * 1024, hb);
        // qkv: 64x64 tiles, grid 1536 (6 blocks/CU) for latency hiding
        k_gemm64<0><<<1536, 256, 0, stream>>>(hb, wT, attn_b + i * 3072,
                                              nullptr, nullptr, qkvb, 3072, 1024);
        if (i < 5) {
            int j = i + 1;
            k_attn_tr<<<3584, 256, 0, stream>>>(qkvb, yb,
                attn_w + (size_t)j * 1024 * 3072, proj_w + (size_t)j * 1024 * 1024,
                mlp_w1 + (size_t)j * 1024 * 4096, mlp_w2 + (size_t)j * 4096 * 1024,
                slots[j & 1], nullptr, nullptr);
        } else {
            k_attn_tr<<<8512, 256, 0, stream>>>(qkvb, yb,
                nullptr, nullptr, nullptr, nullptr, nullptr, out_w, outT);
        }
        k_gemm64<1><<<512, 256, 0, stream>>>(yb, wT + 3145728, proj_b + i * 1024,
                                             x, x, nullptr, 1024, 1024);
        k_ln<<<2048, 256, 0, stream>>>(x, ln2_g + i * 1024, ln2_b + i * 1024, hb);
        k_gemm2<0><<<512, 256, 0, stream>>>(hb, wT + 4194304, mlp_b1 + i * 4096,
                                            nullptr, nullptr, hidb, 4096, 1024);
        k_gemm64<2><<<512, 256, 0, stream>>>(hidb, wT + 8388608, mlp_b2 + i * 1024,
                                             x, x, (i == 5) ? hb : nullptr, 1024, 4096);
    }

    // logits: 128x128 m97-structure at 2 blocks/CU -> epilogue overlaps K-loop
    k_gemm2<3><<<4000, 256, 0, stream>>>(hb, outT, nullptr, nullptr, out, nullptr,
                                         32000, 1024);
}

// Round 12
// 1131.581 us; speedup vs baseline: 1.0572x; 1.0572x over previous
//
#include <hip/hip_runtime.h>
#include <hip/hip_bf16.h>
#include <math.h>

typedef __bf16 bf16;
typedef __bf16 bf16x4 __attribute__((ext_vector_type(4)));
typedef __bf16 bf16x8 __attribute__((ext_vector_type(8)));
typedef float f32x4 __attribute__((ext_vector_type(4)));

__device__ __forceinline__ void gld_lds16(const void* g, void* l) {
    __builtin_amdgcn_global_load_lds(
        (const __attribute__((address_space(1))) unsigned int*)g,
        (__attribute__((address_space(3))) unsigned int*)l, 16, 0, 0);
}

#define VMW(n) asm volatile("s_waitcnt vmcnt(" #n ")" ::: "memory")
#define BARR() asm volatile("s_barrier" ::: "memory")

// ---------------- embedding + positional ----------------
__global__ __launch_bounds__(256) void k_embed(const int* __restrict__ tok,
                                               const float* __restrict__ emb,
                                               const float* __restrict__ pos,
                                               float* __restrict__ x) {
    int row = blockIdx.x;
    int l = row & 1023;
    int tk = tok[row];
    const float4* e = (const float4*)(emb + (size_t)tk * 1024);
    const float4* p = (const float4*)(pos + (size_t)l * 1024);
    float4* o = (float4*)(x + (size_t)row * 1024);
    float4 a = e[threadIdx.x], b = p[threadIdx.x];
    o[threadIdx.x] = make_float4(a.x + b.x, a.y + b.y, a.z + b.z, a.w + b.w);
}

// ---------------- layernorm (f32 in, bf16 out) ----------------
__global__ __launch_bounds__(256) void k_ln(const float* __restrict__ x,
                                            const float* __restrict__ g,
                                            const float* __restrict__ b,
                                            bf16* __restrict__ out) {
    int row = blockIdx.x;
    int t = threadIdx.x;
    const float4* xr = (const float4*)(x + (size_t)row * 1024);
    float4 v = xr[t];
    float s1 = v.x + v.y + v.z + v.w;
    float s2 = v.x * v.x + v.y * v.y + v.z * v.z + v.w * v.w;
#pragma unroll
    for (int o = 32; o; o >>= 1) { s1 += __shfl_down(s1, o); s2 += __shfl_down(s2, o); }
    __shared__ float ps1[4], ps2[4], stat[2];
    int lane = t & 63, wid = t >> 6;
    if (lane == 0) { ps1[wid] = s1; ps2[wid] = s2; }
    __syncthreads();
    if (t == 0) {
        float a1 = ps1[0] + ps1[1] + ps1[2] + ps1[3];
        float a2 = ps2[0] + ps2[1] + ps2[2] + ps2[3];
        float mu = a1 * (1.f / 1024.f);
        float var = a2 * (1.f / 1024.f) - mu * mu;
        stat[0] = mu; stat[1] = rsqrtf(var + 1e-5f);
    }
    __syncthreads();
    float mu = stat[0], rs = stat[1];
    const float4* gv = (const float4*)g;
    const float4* bv = (const float4*)b;
    float4 gg = gv[t], bb = bv[t];
    bf16x4 o4;
    o4[0] = (bf16)((v.x - mu) * rs * gg.x + bb.x);
    o4[1] = (bf16)((v.y - mu) * rs * gg.y + bb.y);
    o4[2] = (bf16)((v.z - mu) * rs * gg.z + bb.z);
    o4[3] = (bf16)((v.w - mu) * rs * gg.w + bb.w);
    *(bf16x4*)(out + (size_t)row * 1024 + t * 4) = o4;
}

// ---------------- 64x64 transpose+cast device helper ----------------
__device__ __forceinline__ void transpose64(const float* __restrict__ W,
                                            bf16* __restrict__ WT,
                                            int K, int N, int n0, int k0, int t,
                                            float (*tile)[65]) {
    int tx = t & 15, ty = t >> 4;
#pragma unroll
    for (int i = 0; i < 64; i += 16) {
        float4 v = *(const float4*)&W[(size_t)(k0 + ty + i) * N + n0 + tx * 4];
        tile[ty + i][tx * 4 + 0] = v.x;
        tile[ty + i][tx * 4 + 1] = v.y;
        tile[ty + i][tx * 4 + 2] = v.z;
        tile[ty + i][tx * 4 + 3] = v.w;
    }
    __syncthreads();
    int n = t >> 3, ks = t & 7;
#pragma unroll
    for (int pass = 0; pass < 2; ++pass) {
        int nn = n + pass * 32;
        bf16x8 v;
#pragma unroll
        for (int j = 0; j < 8; ++j) v[j] = (bf16)tile[ks * 8 + j][nn];
        *(bf16x8*)&WT[(size_t)(n0 + nn) * K + k0 + ks * 8] = v;
    }
}

__device__ __forceinline__ void tr_layer_block(int bid,
                                               const float* aw, const float* pw,
                                               const float* m1, const float* m2,
                                               bf16* wT, int t, float (*tile)[65]) {
    const float* src; bf16* dst; int K, N, tn, tk;
    if (bid < 768)       { src = aw; dst = wT;            K = 1024; N = 3072; tn = bid % 48; tk = bid / 48; }
    else if (bid < 1024) { int b = bid - 768;  src = pw; dst = wT + 3145728; K = 1024; N = 1024; tn = b % 16; tk = b / 16; }
    else if (bid < 2048) { int b = bid - 1024; src = m1; dst = wT + 4194304; K = 1024; N = 4096; tn = b % 64; tk = b / 64; }
    else                 { int b = bid - 2048; src = m2; dst = wT + 8388608; K = 4096; N = 1024; tn = b % 16; tk = b / 16; }
    transpose64(src, dst, K, N, tn * 64, tk * 64, t, tile);
}

__global__ __launch_bounds__(256) void k_transpose_layer(const float* __restrict__ aw,
                                                         const float* __restrict__ pw,
                                                         const float* __restrict__ m1,
                                                         const float* __restrict__ m2,
                                                         bf16* __restrict__ wT) {
    __shared__ float tile[64][65];
    tr_layer_block(blockIdx.x, aw, pw, m1, m2, wT, threadIdx.x, tile);
}

// ---------------- 128x128 GEMM, double-buffered 2-phase + T2 swizzle ----------------
__device__ __forceinline__ void stage128(const char* Ab, const char* Bb,
                                         char* As, char* Bs, int Kb, int k0b, int t) {
#pragma unroll
    for (int j = 0; j < 4; ++j) {
        int idx = j * 256 + t;
        int row = idx >> 3;
        int cb = (idx & 7) << 4;
        int scb = cb ^ ((row & 7) << 4);
        gld_lds16(Ab + (size_t)row * Kb + k0b + scb, As + idx * 16);
        gld_lds16(Bb + (size_t)row * Kb + k0b + scb, Bs + idx * 16);
    }
}

template <int EPI>
__global__ __launch_bounds__(256) void k_gemm2(const bf16* __restrict__ A,
                                               const bf16* __restrict__ BT,
                                               const float* __restrict__ bias,
                                               const float* __restrict__ resid,
                                               float* __restrict__ outf,
                                               bf16* __restrict__ outb,
                                               int N, int K) {
    __shared__ __align__(16) bf16 As[2][128 * 64];
    __shared__ __align__(16) bf16 Bs[2][128 * 64];
    int per = gridDim.x >> 3;
    int tile = (blockIdx.x & 7) * per + (blockIdx.x >> 3);
    int bm = tile & 15, bn = tile >> 4;
    int t = threadIdx.x, lane = t & 63;
    int wr = t >> 7, wc = (t >> 6) & 1;
    f32x4 acc[4][4] = {};
    const char* Ab = (const char*)(A + (size_t)bm * 128 * K);
    const char* Bb = (const char*)(BT + (size_t)bn * 128 * K);
    int Kb = K * 2;
    int nk = K >> 6;
    stage128(Ab, Bb, (char*)As[0], (char*)Bs[0], Kb, 0, t);
    VMW(0); BARR();
    for (int tt = 0; tt < nk; ++tt) {
        int cur = tt & 1;
        if (tt + 1 < nk)
            stage128(Ab, Bb, (char*)As[cur ^ 1], (char*)Bs[cur ^ 1], Kb, (tt + 1) * 128, t);
        const char* Ac = (const char*)As[cur];
        const char* Bc = (const char*)Bs[cur];
#pragma unroll
        for (int kk = 0; kk < 2; ++kk) {
            bf16x8 af[4], bfr[4];
            int cb = kk * 64 + ((lane >> 4) << 4);
#pragma unroll
            for (int m = 0; m < 4; ++m) {
                int r = wr * 64 + m * 16 + (lane & 15);
                af[m] = *(const bf16x8*)(Ac + r * 128 + (cb ^ ((r & 7) << 4)));
            }
#pragma unroll
            for (int n = 0; n < 4; ++n) {
                int r = wc * 64 + n * 16 + (lane & 15);
                bfr[n] = *(const bf16x8*)(Bc + r * 128 + (cb ^ ((r & 7) << 4)));
            }
#pragma unroll
            for (int m = 0; m < 4; ++m)
#pragma unroll
                for (int n = 0; n < 4; ++n)
                    acc[m][n] = __builtin_amdgcn_mfma_f32_16x16x32_bf16(af[m], bfr[n], acc[m][n], 0, 0, 0);
        }
        VMW(0); BARR();
    }
    int row0 = bm * 128 + wr * 64 + ((lane >> 4) << 2);
    int col0 = bn * 128 + wc * 64 + (lane & 15);
#pragma unroll
    for (int m = 0; m < 4; ++m) {
#pragma unroll
        for (int n = 0; n < 4; ++n) {
            int col = col0 + n * 16;
            float bv = bias[col];
#pragma unroll
            for (int r = 0; r < 4; ++r) {
                int row = row0 + m * 16 + r;
                size_t idx = (size_t)row * N + col;
                float v = acc[m][n][r] + bv;
                if (EPI == 0) {
                    outb[idx] = (bf16)v;
                } else if (EPI == 1) {
                    outf[idx] = resid[idx] + v;
                } else {
                    outf[idx] = resid[idx] + 0.5f * v * (1.0f + erff(v * 0.70710678118f));
                }
            }
        }
    }
}

// ---------------- 64x64 GEMM (proj, mlp2) ----------------
__device__ __forceinline__ void stage64(const char* Ab, const char* Bb,
                                        char* As, char* Bs, int Kb, int k0b, int t) {
#pragma unroll
    for (int j = 0; j < 2; ++j) {
        int idx = j * 256 + t;
        int row = idx >> 3;
        int cb = (idx & 7) << 4;
        int scb = cb ^ ((row & 7) << 4);
        gld_lds16(Ab + (size_t)row * Kb + k0b + scb, As + idx * 16);
        gld_lds16(Bb + (size_t)row * Kb + k0b + scb, Bs + idx * 16);
    }
}

template <int EPI>
__global__ __launch_bounds__(256) void k_gemm64(const bf16* __restrict__ A,
                                                const bf16* __restrict__ BT,
                                                const float* __restrict__ bias,
                                                const float* __restrict__ resid,
                                                float* __restrict__ outf,
                                                bf16* __restrict__ outb,
                                                int N, int K) {
    __shared__ __align__(16) bf16 As[2][64 * 64];
    __shared__ __align__(16) bf16 Bs[2][64 * 64];
    int per = gridDim.x >> 3;
    int tile = (blockIdx.x & 7) * per + (blockIdx.x >> 3);
    int bm = tile & 31, bn = tile >> 5;
    int t = threadIdx.x, lane = t & 63, wid = t >> 6;
    f32x4 acc[4] = {};
    const char* Ab = (const char*)(A + (size_t)bm * 64 * K);
    const char* Bb = (const char*)(BT + (size_t)bn * 64 * K);
    int Kb = K * 2;
    int nk = K >> 6;
    stage64(Ab, Bb, (char*)As[0], (char*)Bs[0], Kb, 0, t);
    VMW(0); BARR();
    for (int tt = 0; tt < nk; ++tt) {
        int cur = tt & 1;
        if (tt + 1 < nk)
            stage64(Ab, Bb, (char*)As[cur ^ 1], (char*)Bs[cur ^ 1], Kb, (tt + 1) * 128, t);
        const char* Ac = (const char*)As[cur];
        const char* Bc = (const char*)Bs[cur];
#pragma unroll
        for (int kk = 0; kk < 2; ++kk) {
            int cb = kk * 64 + ((lane >> 4) << 4);
            int ra = wid * 16 + (lane & 15);
            bf16x8 af = *(const bf16x8*)(Ac + ra * 128 + (cb ^ ((ra & 7) << 4)));
            bf16x8 bfr[4];
#pragma unroll
            for (int n = 0; n < 4; ++n) {
                int r = n * 16 + (lane & 15);
                bfr[n] = *(const bf16x8*)(Bc + r * 128 + (cb ^ ((r & 7) << 4)));
            }
#pragma unroll
            for (int n = 0; n < 4; ++n)
                acc[n] = __builtin_amdgcn_mfma_f32_16x16x32_bf16(af, bfr[n], acc[n], 0, 0, 0);
        }
        VMW(0); BARR();
    }
    int row0 = bm * 64 + wid * 16 + ((lane >> 4) << 2);
    int col0 = bn * 64 + (lane & 15);
#pragma unroll
    for (int n = 0; n < 4; ++n) {
        int col = col0 + n * 16;
        float bv = bias[col];
#pragma unroll
        for (int r = 0; r < 4; ++r) {
            int row = row0 + r;
            size_t idx = (size_t)row * N + col;
            float v = acc[n][r] + bv;
            float res;
            if (EPI == 1) {
                res = resid[idx] + v;
            } else {
                res = resid[idx] + 0.5f * v * (1.0f + erff(v * 0.70710678118f));
            }
            outf[idx] = res;
            if (outb) outb[idx] = (bf16)res;   // fused final cast (layer 5 mlp2)
        }
    }
}

// ---------------- 256x256 GEMM (logits): phased K-loop ------------------
__device__ __forceinline__ void stage_full256(const char* gtile, char* ldst,
                                              int Kb, int t) {
#pragma unroll
    for (int j = 0; j < 4; ++j) {
        int idx = j * 512 + t;
        int row = idx >> 3;
        int cb = (idx & 7) << 4;
        int scb = cb ^ ((row & 7) << 4);
        gld_lds16(gtile + (size_t)row * Kb + scb, ldst + idx * 16);
    }
}

__device__ __forceinline__ void stage_half256(const char* gtile, char* ldst,
                                              int Kb, int t, int half) {
#pragma unroll
    for (int j = 0; j < 2; ++j) {
        int idx = (half * 2 + j) * 512 + t;
        int row = idx >> 3;
        int cb = (idx & 7) << 4;
        int scb = cb ^ ((row & 7) << 4);
        gld_lds16(gtile + (size_t)row * Kb + scb, ldst + idx * 16);
    }
}

template <int MH, int NH>
__device__ __forceinline__ void phase_rd(const char* Ac, const char* Bc,
                                         int lrow, int lk, int wm, int wn,
                                         bf16x8 (&af)[4][2], bf16x8 (&bfr)[2][2]) {
#pragma unroll
    for (int kk = 0; kk < 2; ++kk) {
        int cb = kk * 64 + lk * 16;
#pragma unroll
        for (int m = 0; m < 4; ++m) {
            int row = (MH * 4 + m) * 32 + wm * 16 + lrow;
            af[m][kk] = *(const bf16x8*)(Ac + row * 128 + (cb ^ ((row & 7) << 4)));
        }
#pragma unroll
        for (int n = 0; n < 2; ++n) {
            int row = (NH * 2 + n) * 64 + wn * 16 + lrow;
            bfr[n][kk] = *(const bf16x8*)(Bc + row * 128 + (cb ^ ((row & 7) << 4)));
        }
    }
}

template <int MH, int NH>
__device__ __forceinline__ void phase_mm(bf16x8 (&af)[4][2], bf16x8 (&bfr)[2][2],
                                         f32x4 (&acc)[8][4]) {
    __builtin_amdgcn_s_setprio(1);
#pragma unroll
    for (int kk = 0; kk < 2; ++kk)
#pragma unroll
        for (int m = 0; m < 4; ++m)
#pragma unroll
            for (int n = 0; n < 2; ++n)
                acc[MH * 4 + m][NH * 2 + n] = __builtin_amdgcn_mfma_f32_16x16x32_bf16(
                    af[m][kk], bfr[n][kk], acc[MH * 4 + m][NH * 2 + n], 0, 0, 0);
    __builtin_amdgcn_s_setprio(0);
    __builtin_amdgcn_sched_barrier(0);
}

__global__ __launch_bounds__(512, 1) void k_gemm256(const bf16* __restrict__ A,
                                                    const bf16* __restrict__ BT,
                                                    float* __restrict__ outf,
                                                    int N, int K) {
    __shared__ __align__(16) bf16 Asb[2][256 * 64];
    __shared__ __align__(16) bf16 Bsb[3][256 * 64];
    int t = threadIdx.x, lane = t & 63, wid = t >> 6;
    int wm = wid >> 2, wn = wid & 3;
    int lrow = lane & 15, lk = lane >> 4;
    int tile = (blockIdx.x & 7) * 125 + (blockIdx.x >> 3);
    int bm = tile & 7;
    int bn = tile >> 3;

    const char* Ab = (const char*)(A + (size_t)bm * 256 * K);
    const char* Bb = (const char*)(BT + (size_t)bn * 256 * K);
    int Kb = K * 2;
    int nk = K >> 6;
    f32x4 acc[8][4] = {};

    stage_full256(Ab, (char*)Asb[0], Kb, t);
    stage_full256(Bb, (char*)Bsb[0], Kb, t);
    stage_full256(Bb + 128, (char*)Bsb[1], Kb, t);

    for (int tt = 0; tt < nk; ++tt) {
        int ka = (tt + 1 < nk) ? tt + 1 : nk - 1;
        int kb = (tt + 2 < nk) ? tt + 2 : nk - 1;
        const char* Ac = (const char*)Asb[tt & 1];
        const char* Bc = (const char*)Bsb[tt % 3];
        char* An = (char*)Asb[(tt + 1) & 1];
        char* Bn = (char*)Bsb[(tt + 2) % 3];
        const char* Ag = Ab + (size_t)ka * 128;
        const char* Bg = Bb + (size_t)kb * 128;
        VMW(4); BARR();
        bf16x8 af[4][2], bfr[2][2];
        phase_rd<0, 0>(Ac, Bc, lrow, lk, wm, wn, af, bfr);
        stage_half256(Ag, An, Kb, t, 0);
        BARR();
        phase_mm<0, 0>(af, bfr, acc);
        BARR();
        phase_rd<0, 1>(Ac, Bc, lrow, lk, wm, wn, af, bfr);
        stage_half256(Ag, An, Kb, t, 1);
        BARR();
        phase_mm<0, 1>(af, bfr, acc);
        BARR();
        phase_rd<1, 0>(Ac, Bc, lrow, lk, wm, wn, af, bfr);
        stage_half256(Bg, Bn, Kb, t, 0);
        BARR();
        phase_mm<1, 0>(af, bfr, acc);
        BARR();
        phase_rd<1, 1>(Ac, Bc, lrow, lk, wm, wn, af, bfr);
        stage_half256(Bg, Bn, Kb, t, 1);
        BARR();
        phase_mm<1, 1>(af, bfr, acc);
        BARR();
    }

    size_t row0 = (size_t)bm * 256 + wm * 16 + (lane >> 4) * 4;
    int col0 = bn * 256 + wn * 16 + (lane & 15);
#pragma unroll
    for (int mi = 0; mi < 8; ++mi) {
#pragma unroll
        for (int ni = 0; ni < 4; ++ni) {
            int col = col0 + ni * 64;
#pragma unroll
            for (int r = 0; r < 4; ++r) {
                size_t row = row0 + mi * 32 + r;
                outf[row * N + col] = acc[mi][ni][r];
            }
        }
    }
}

// ---------------- heterogeneous: flash attention + weight transpose ----------------
// Attn: K/V double-buffered, prefetch issued BEFORE compute (T14): stage K(t+1)
// via gld_lds + load V(t+1) to regs, compute tile t, then vmcnt(0) + V reg->LDS
// write. One barrier per tile; staging latency hides under QK^T/softmax/PV.
__global__ __launch_bounds__(256) void k_attn_tr(const bf16* __restrict__ qkv,
                                                 bf16* __restrict__ y,
                                                 const float* __restrict__ aw,
                                                 const float* __restrict__ pw,
                                                 const float* __restrict__ m1,
                                                 const float* __restrict__ m2,
                                                 bf16* __restrict__ wTnext,
                                                 const float* __restrict__ outw,
                                                 bf16* __restrict__ outT) {
    __shared__ __align__(16) char smem[49152];
    int bidg = blockIdx.x;
    int t = threadIdx.x;
    if (bidg >= 512) {
        int tb = bidg - 512;
        float (*tile)[65] = (float(*)[65])smem;
        if (aw) {
            tr_layer_block(tb, aw, pw, m1, m2, wTnext, t, tile);
        } else {
            int tn = tb % 500, tk = tb / 500;
            transpose64(outw, outT, 1024, 32000, tn * 64, tk * 64, t, tile);
        }
        return;
    }
    bf16* Qs  = (bf16*)smem;
    bf16* KsA = Qs + 4096;
    bf16* KsB = KsA + 4096;
    bf16* VtA = KsB + 4096;
    bf16* VtB = VtA + 4096;
    bf16* Ps  = VtB + 4096;
    int tile = (bidg & 7) * 64 + (bidg >> 3);
    int qb = tile & 15;
    int bh = tile >> 4;
    int b = bh >> 4, h = bh & 15;
    int lane = t & 63, wid = t >> 6;
    int lr = lane & 15, lk = lane >> 4;
    int tok0 = b << 10;
    int q0 = qb << 6;
    const char* qbase = (const char*)qkv;
    int kvr = t >> 2, d0v = (t & 3) * 16;

    auto stageK = [&](int kv0, bf16* Kb) {
#pragma unroll
        for (int j = 0; j < 2; ++j) {
            int off = (j * 256 + t) * 16;
            int row = off >> 7, colb = off & 127;
            int scb = colb ^ ((row & 7) << 4);
            gld_lds16(qbase + ((size_t)(tok0 + kv0 + row) * 3072 + 1024 + h * 64) * 2 + scb,
                      (char*)Kb + off);
        }
    };
    bf16x4 vreg[4];
    auto loadV = [&](int kv0) {
        const bf16* vrow = qkv + (size_t)(tok0 + kv0 + kvr) * 3072 + 2048 + h * 64 + d0v;
#pragma unroll
        for (int e4 = 0; e4 < 4; ++e4) vreg[e4] = *(const bf16x4*)(vrow + e4 * 4);
    };
    auto writeV = [&](bf16* Vb) {
#pragma unroll
        for (int e4 = 0; e4 < 4; ++e4)
#pragma unroll
            for (int i2 = 0; i2 < 4; ++i2) {
                int d = d0v + e4 * 4 + i2;
                Vb[d * 64 + (kvr ^ ((d & 7) << 3))] = vreg[e4][i2];
            }
    };

    // prologue: stage Q + K(0) (gld_lds) and V(0) (regs) concurrently
#pragma unroll
    for (int j = 0; j < 2; ++j) {
        int off = (j * 256 + t) * 16;
        int row = off >> 7, colb = off & 127;
        int scb = colb ^ ((row & 7) << 4);
        gld_lds16(qbase + ((size_t)(tok0 + q0 + row) * 3072 + h * 64) * 2 + scb, (char*)Qs + off);
    }
    stageK(0, KsA);
    loadV(0);
    VMW(0);
    writeV(VtA);
    __syncthreads();

    int qrw = wid * 16 + lr;
    int qsw = (qrw & 7) << 4;
    bf16x8 aq0 = *(const bf16x8*)((const char*)Qs + qrw * 128 + ((lk * 16) ^ qsw));
    bf16x8 aq1 = *(const bf16x8*)((const char*)Qs + qrw * 128 + ((64 + lk * 16) ^ qsw));
    f32x4 o[4] = {};
    float mrun[4], lrun[4];
#pragma unroll
    for (int r = 0; r < 4; ++r) { mrun[r] = -INFINITY; lrun[r] = 0.f; }
    int qrow = q0 + wid * 16 + lk * 4;
    int nt = qb + 1;

    for (int ti = 0; ti < nt; ++ti) {
        int kv0 = ti << 6;
        bf16* Kc = (ti & 1) ? KsB : KsA;
        bf16* Vc = (ti & 1) ? VtB : VtA;
        bf16* Kn = (ti & 1) ? KsA : KsB;
        bf16* Vn = (ti & 1) ? VtA : VtB;
        bool pf = (ti + 1 < nt);
        if (pf) { stageK((ti + 1) << 6, Kn); loadV((ti + 1) << 6); }
        // S = Q K^T on current buffers
        f32x4 s[4];
#pragma unroll
        for (int n = 0; n < 4; ++n) {
            int krw = n * 16 + lr;
            int ksw = (krw & 7) << 4;
            const char* kb = (const char*)Kc + krw * 128;
            bf16x8 bk0 = *(const bf16x8*)(kb + ((lk * 16) ^ ksw));
            bf16x8 bk1 = *(const bf16x8*)(kb + ((64 + lk * 16) ^ ksw));
            f32x4 z = {};
            z = __builtin_amdgcn_mfma_f32_16x16x32_bf16(aq0, bk0, z, 0, 0, 0);
            z = __builtin_amdgcn_mfma_f32_16x16x32_bf16(aq1, bk1, z, 0, 0, 0);
            s[n] = z;
        }
        float mx[4];
#pragma unroll
        for (int r = 0; r < 4; ++r) mx[r] = -INFINITY;
#pragma unroll
        for (int n = 0; n < 4; ++n) {
            int col = kv0 + n * 16 + lr;
#pragma unroll
            for (int r = 0; r < 4; ++r) {
                float sv = s[n][r] * 0.125f;
                sv = (col <= qrow + r) ? sv : -INFINITY;
                s[n][r] = sv;
                mx[r] = fmaxf(mx[r], sv);
            }
        }
#pragma unroll
        for (int r = 0; r < 4; ++r)
#pragma unroll
            for (int m = 1; m < 16; m <<= 1) mx[r] = fmaxf(mx[r], __shfl_xor(mx[r], m));
        float scl[4];
#pragma unroll
        for (int r = 0; r < 4; ++r) {
            float mn = fmaxf(mrun[r], mx[r]);
            scl[r] = __expf(mrun[r] - mn);
            mrun[r] = mn;
        }
        float rs[4] = {0.f, 0.f, 0.f, 0.f};
#pragma unroll
        for (int n = 0; n < 4; ++n)
#pragma unroll
            for (int r = 0; r < 4; ++r) {
                float p = __expf(s[n][r] - mrun[r]);
                s[n][r] = p;
                rs[r] += p;
            }
#pragma unroll
        for (int r = 0; r < 4; ++r) {
#pragma unroll
            for (int m = 1; m < 16; m <<= 1) rs[r] += __shfl_xor(rs[r], m);
            lrun[r] = lrun[r] * scl[r] + rs[r];
        }
#pragma unroll
        for (int n = 0; n < 4; ++n)
#pragma unroll
            for (int r = 0; r < 4; ++r) {
                o[n][r] *= scl[r];
                int prow = lk * 4 + r;
                Ps[wid * 1024 + prow * 64 + ((n * 16 + lr) ^ ((prow & 7) << 3))] = (bf16)s[n][r];
            }
        int psw = (lr & 7) << 3;
        const bf16* pb = Ps + wid * 1024 + lr * 64;
        bf16x8 ap0 = *(const bf16x8*)(pb + ((lk * 8) ^ psw));
        bf16x8 ap1 = *(const bf16x8*)(pb + ((32 + lk * 8) ^ psw));
#pragma unroll
        for (int n = 0; n < 4; ++n) {
            int vrw = n * 16 + lr;
            int vsw = (vrw & 7) << 3;
            const bf16* vb = Vc + vrw * 64;
            bf16x8 bv0 = *(const bf16x8*)(vb + ((lk * 8) ^ vsw));
            bf16x8 bv1 = *(const bf16x8*)(vb + ((32 + lk * 8) ^ vsw));
            o[n] = __builtin_amdgcn_mfma_f32_16x16x32_bf16(ap0, bv0, o[n], 0, 0, 0);
            o[n] = __builtin_amdgcn_mfma_f32_16x16x32_bf16(ap1, bv1, o[n], 0, 0, 0);
        }
        if (pf) { VMW(0); writeV(Vn); }
        __syncthreads();
    }
#pragma unroll
    for (int n = 0; n < 4; ++n)
#pragma unroll
        for (int r = 0; r < 4; ++r) {
            int row = tok0 + qrow + r;
            y[(size_t)row * 1024 + h * 64 + n * 16 + lr] = (bf16)(o[n][r] / lrun[r]);
        }
}

extern "C" void kernel_launch(void* const* d_in, const int* in_sizes, int n_in,
                              void* d_out, int out_size, void* d_ws, size_t ws_size,
                              hipStream_t stream) {
    const int*   tokens = (const int*)d_in[0];
    const float* pos    = (const float*)d_in[1];
    const float* emb    = (const float*)d_in[2];
    const float* ln1_g  = (const float*)d_in[3];
    const float* ln1_b  = (const float*)d_in[4];
    const float* ln2_g  = (const float*)d_in[5];
    const float* ln2_b  = (const float*)d_in[6];
    const float* attn_w = (const float*)d_in[7];
    const float* attn_b = (const float*)d_in[8];
    const float* proj_w = (const float*)d_in[9];
    const float* proj_b = (const float*)d_in[10];
    const float* mlp_w1 = (const float*)d_in[11];
    const float* mlp_b1 = (const float*)d_in[12];
    const float* mlp_w2 = (const float*)d_in[13];
    const float* mlp_b2 = (const float*)d_in[14];
    const float* out_w  = (const float*)d_in[15];
    float* out = (float*)d_out;

    char* ws = (char*)d_ws;
    size_t off = 0;
    auto alloc = [&](size_t bytes) {
        void* p = ws + off;
        off = (off + bytes + 255) & ~(size_t)255;
        return p;
    };
    float* x   = (float*)alloc((size_t)2048 * 1024 * 4);
    bf16* hb   = (bf16*)alloc((size_t)2048 * 1024 * 2);
    bf16* qkvb = (bf16*)alloc((size_t)2048 * 3072 * 2);
    bf16* yb   = (bf16*)alloc((size_t)2048 * 1024 * 2);
    bf16* hidb = (bf16*)alloc((size_t)2048 * 4096 * 2);
    // outT (32000x1024) doubles as wT slot0 in its first 9437184 elements:
    // slot0's last read (layer-4 mlp2) precedes outT's write (layer-5 attn launch).
    bf16* outT = (bf16*)alloc((size_t)32000 * 1024 * 2);
    bf16* slot1 = (bf16*)alloc((size_t)9437184 * 2);
    bf16* slots[2] = { outT, slot1 };

    k_embed<<<2048, 256, 0, stream>>>(tokens, emb, pos, x);
    k_transpose_layer<<<3072, 256, 0, stream>>>(attn_w, proj_w, mlp_w1, mlp_w2, slots[0]);

    for (int i = 0; i < 6; ++i) {
        bf16* wT = slots[i & 1];
        k_ln<<<2048, 256, 0, stream>>>(x, ln1_g + i * 1024, ln1_b + i * 1024, hb);
        k_gemm2<0><<<384, 256, 0, stream>>>(hb, wT, attn_b + i * 3072,
                                            nullptr, nullptr, qkvb, 3072, 1024);
        if (i < 5) {
            int j = i + 1;
            k_attn_tr<<<3584, 256, 0, stream>>>(qkvb, yb,
                attn_w + (size_t)j * 1024 * 3072, proj_w + (size_t)j * 1024 * 1024,
                mlp_w1 + (size_t)j * 1024 * 4096, mlp_w2 + (size_t)j * 4096 * 1024,
                slots[j & 1], nullptr, nullptr);
        } else {
            k_attn_tr<<<8512, 256, 0, stream>>>(qkvb, yb,
                nullptr, nullptr, nullptr, nullptr, nullptr, out_w, outT);
        }
        k_gemm64<1><<<512, 256, 0, stream>>>(yb, wT + 3145728, proj_b + i * 1024,
                                             x, x, nullptr, 1024, 1024);
        k_ln<<<2048, 256, 0, stream>>>(x, ln2_g + i * 1024, ln2_b + i * 1024, hb);
        k_gemm2<0><<<512, 256, 0, stream>>>(hb, wT + 4194304, mlp_b1 + i * 4096,
                                            nullptr, nullptr, hidb, 4096, 1024);
        k_gemm64<2><<<512, 256, 0, stream>>>(hidb, wT + 8388608, mlp_b2 + i * 1024,
                                             x, x, (i == 5) ? hb : nullptr, 1024, 4096);
    }

    k_gemm256<<<1000, 512, 0, stream>>>(hb, outT, out, 32000, 1024);
}

// Round 13
// 1098.441 us; speedup vs baseline: 1.0891x; 1.0302x over previous
//
#include <hip/hip_runtime.h>
#include <hip/hip_bf16.h>
#include <math.h>

typedef __bf16 bf16;
typedef __bf16 bf16x4 __attribute__((ext_vector_type(4)));
typedef __bf16 bf16x8 __attribute__((ext_vector_type(8)));
typedef float f32x4 __attribute__((ext_vector_type(4)));

__device__ __forceinline__ void gld_lds16(const void* g, void* l) {
    __builtin_amdgcn_global_load_lds(
        (const __attribute__((address_space(1))) unsigned int*)g,
        (__attribute__((address_space(3))) unsigned int*)l, 16, 0, 0);
}

#define VMW(n) asm volatile("s_waitcnt vmcnt(" #n ")" ::: "memory")
#define BARR() asm volatile("s_barrier" ::: "memory")

// ---------------- embedding + positional ----------------
__global__ __launch_bounds__(256) void k_embed(const int* __restrict__ tok,
                                               const float* __restrict__ emb,
                                               const float* __restrict__ pos,
                                               float* __restrict__ x) {
    int row = blockIdx.x;
    int l = row & 1023;
    int tk = tok[row];
    const float4* e = (const float4*)(emb + (size_t)tk * 1024);
    const float4* p = (const float4*)(pos + (size_t)l * 1024);
    float4* o = (float4*)(x + (size_t)row * 1024);
    float4 a = e[threadIdx.x], b = p[threadIdx.x];
    o[threadIdx.x] = make_float4(a.x + b.x, a.y + b.y, a.z + b.z, a.w + b.w);
}

// ---------------- layernorm (f32 in, bf16 out) ----------------
__global__ __launch_bounds__(256) void k_ln(const float* __restrict__ x,
                                            const float* __restrict__ g,
                                            const float* __restrict__ b,
                                            bf16* __restrict__ out) {
    int row = blockIdx.x;
    int t = threadIdx.x;
    const float4* xr = (const float4*)(x + (size_t)row * 1024);
    float4 v = xr[t];
    float s1 = v.x + v.y + v.z + v.w;
    float s2 = v.x * v.x + v.y * v.y + v.z * v.z + v.w * v.w;
#pragma unroll
    for (int o = 32; o; o >>= 1) { s1 += __shfl_down(s1, o); s2 += __shfl_down(s2, o); }
    __shared__ float ps1[4], ps2[4], stat[2];
    int lane = t & 63, wid = t >> 6;
    if (lane == 0) { ps1[wid] = s1; ps2[wid] = s2; }
    __syncthreads();
    if (t == 0) {
        float a1 = ps1[0] + ps1[1] + ps1[2] + ps1[3];
        float a2 = ps2[0] + ps2[1] + ps2[2] + ps2[3];
        float mu = a1 * (1.f / 1024.f);
        float var = a2 * (1.f / 1024.f) - mu * mu;
        stat[0] = mu; stat[1] = rsqrtf(var + 1e-5f);
    }
    __syncthreads();
    float mu = stat[0], rs = stat[1];
    const float4* gv = (const float4*)g;
    const float4* bv = (const float4*)b;
    float4 gg = gv[t], bb = bv[t];
    bf16x4 o4;
    o4[0] = (bf16)((v.x - mu) * rs * gg.x + bb.x);
    o4[1] = (bf16)((v.y - mu) * rs * gg.y + bb.y);
    o4[2] = (bf16)((v.z - mu) * rs * gg.z + bb.z);
    o4[3] = (bf16)((v.w - mu) * rs * gg.w + bb.w);
    *(bf16x4*)(out + (size_t)row * 1024 + t * 4) = o4;
}

// ---------------- 64x64 transpose+cast device helper ----------------
__device__ __forceinline__ void transpose64(const float* __restrict__ W,
                                            bf16* __restrict__ WT,
                                            int K, int N, int n0, int k0, int t,
                                            float (*tile)[65]) {
    int tx = t & 15, ty = t >> 4;
#pragma unroll
    for (int i = 0; i < 64; i += 16) {
        float4 v = *(const float4*)&W[(size_t)(k0 + ty + i) * N + n0 + tx * 4];
        tile[ty + i][tx * 4 + 0] = v.x;
        tile[ty + i][tx * 4 + 1] = v.y;
        tile[ty + i][tx * 4 + 2] = v.z;
        tile[ty + i][tx * 4 + 3] = v.w;
    }
    __syncthreads();
    int n = t >> 3, ks = t & 7;
#pragma unroll
    for (int pass = 0; pass < 2; ++pass) {
        int nn = n + pass * 32;
        bf16x8 v;
#pragma unroll
        for (int j = 0; j < 8; ++j) v[j] = (bf16)tile[ks * 8 + j][nn];
        *(bf16x8*)&WT[(size_t)(n0 + nn) * K + k0 + ks * 8] = v;
    }
}

__device__ __forceinline__ void tr_layer_block(int bid,
                                               const float* aw, const float* pw,
                                               const float* m1, const float* m2,
                                               bf16* wT, int t, float (*tile)[65]) {
    const float* src; bf16* dst; int K, N, tn, tk;
    if (bid < 768)       { src = aw; dst = wT;            K = 1024; N = 3072; tn = bid % 48; tk = bid / 48; }
    else if (bid < 1024) { int b = bid - 768;  src = pw; dst = wT + 3145728; K = 1024; N = 1024; tn = b % 16; tk = b / 16; }
    else if (bid < 2048) { int b = bid - 1024; src = m1; dst = wT + 4194304; K = 1024; N = 4096; tn = b % 64; tk = b / 64; }
    else                 { int b = bid - 2048; src = m2; dst = wT + 8388608; K = 4096; N = 1024; tn = b % 16; tk = b / 16; }
    transpose64(src, dst, K, N, tn * 64, tk * 64, t, tile);
}

__global__ __launch_bounds__(256) void k_transpose_layer(const float* __restrict__ aw,
                                                         const float* __restrict__ pw,
                                                         const float* __restrict__ m1,
                                                         const float* __restrict__ m2,
                                                         bf16* __restrict__ wT) {
    __shared__ float tile[64][65];
    tr_layer_block(blockIdx.x, aw, pw, m1, m2, wT, threadIdx.x, tile);
}

// ---------------- 128x128 GEMM, double-buffered 2-phase + T2 swizzle ----------------
__device__ __forceinline__ void stage128(const char* Ab, const char* Bb,
                                         char* As, char* Bs, int Kb, int k0b, int t) {
#pragma unroll
    for (int j = 0; j < 4; ++j) {
        int idx = j * 256 + t;
        int row = idx >> 3;
        int cb = (idx & 7) << 4;
        int scb = cb ^ ((row & 7) << 4);
        gld_lds16(Ab + (size_t)row * Kb + k0b + scb, As + idx * 16);
        gld_lds16(Bb + (size_t)row * Kb + k0b + scb, Bs + idx * 16);
    }
}

template <int EPI>
__global__ __launch_bounds__(256) void k_gemm2(const bf16* __restrict__ A,
                                               const bf16* __restrict__ BT,
                                               const float* __restrict__ bias,
                                               const float* __restrict__ resid,
                                               float* __restrict__ outf,
                                               bf16* __restrict__ outb,
                                               int N, int K) {
    __shared__ __align__(16) bf16 As[2][128 * 64];
    __shared__ __align__(16) bf16 Bs[2][128 * 64];
    int per = gridDim.x >> 3;
    int tile = (blockIdx.x & 7) * per + (blockIdx.x >> 3);
    int bm = tile & 15, bn = tile >> 4;
    int t = threadIdx.x, lane = t & 63;
    int wr = t >> 7, wc = (t >> 6) & 1;
    f32x4 acc[4][4] = {};
    const char* Ab = (const char*)(A + (size_t)bm * 128 * K);
    const char* Bb = (const char*)(BT + (size_t)bn * 128 * K);
    int Kb = K * 2;
    int nk = K >> 6;
    stage128(Ab, Bb, (char*)As[0], (char*)Bs[0], Kb, 0, t);
    VMW(0); BARR();
    for (int tt = 0; tt < nk; ++tt) {
        int cur = tt & 1;
        if (tt + 1 < nk)
            stage128(Ab, Bb, (char*)As[cur ^ 1], (char*)Bs[cur ^ 1], Kb, (tt + 1) * 128, t);
        const char* Ac = (const char*)As[cur];
        const char* Bc = (const char*)Bs[cur];
#pragma unroll
        for (int kk = 0; kk < 2; ++kk) {
            bf16x8 af[4], bfr[4];
            int cb = kk * 64 + ((lane >> 4) << 4);
#pragma unroll
            for (int m = 0; m < 4; ++m) {
                int r = wr * 64 + m * 16 + (lane & 15);
                af[m] = *(const bf16x8*)(Ac + r * 128 + (cb ^ ((r & 7) << 4)));
            }
#pragma unroll
            for (int n = 0; n < 4; ++n) {
                int r = wc * 64 + n * 16 + (lane & 15);
                bfr[n] = *(const bf16x8*)(Bc + r * 128 + (cb ^ ((r & 7) << 4)));
            }
#pragma unroll
            for (int m = 0; m < 4; ++m)
#pragma unroll
                for (int n = 0; n < 4; ++n)
                    acc[m][n] = __builtin_amdgcn_mfma_f32_16x16x32_bf16(af[m], bfr[n], acc[m][n], 0, 0, 0);
        }
        VMW(0); BARR();
    }
    int row0 = bm * 128 + wr * 64 + ((lane >> 4) << 2);
    int col0 = bn * 128 + wc * 64 + (lane & 15);
#pragma unroll
    for (int m = 0; m < 4; ++m) {
#pragma unroll
        for (int n = 0; n < 4; ++n) {
            int col = col0 + n * 16;
            float bv = bias[col];
#pragma unroll
            for (int r = 0; r < 4; ++r) {
                int row = row0 + m * 16 + r;
                size_t idx = (size_t)row * N + col;
                float v = acc[m][n][r] + bv;
                if (EPI == 0) {
                    outb[idx] = (bf16)v;
                } else if (EPI == 1) {
                    outf[idx] = resid[idx] + v;
                } else {
                    outf[idx] = resid[idx] + 0.5f * v * (1.0f + erff(v * 0.70710678118f));
                }
            }
        }
    }
}

// ---------------- 64x64 GEMM (proj, mlp2) ----------------
__device__ __forceinline__ void stage64(const char* Ab, const char* Bb,
                                        char* As, char* Bs, int Kb, int k0b, int t) {
#pragma unroll
    for (int j = 0; j < 2; ++j) {
        int idx = j * 256 + t;
        int row = idx >> 3;
        int cb = (idx & 7) << 4;
        int scb = cb ^ ((row & 7) << 4);
        gld_lds16(Ab + (size_t)row * Kb + k0b + scb, As + idx * 16);
        gld_lds16(Bb + (size_t)row * Kb + k0b + scb, Bs + idx * 16);
    }
}

template <int EPI>
__global__ __launch_bounds__(256) void k_gemm64(const bf16* __restrict__ A,
                                                const bf16* __restrict__ BT,
                                                const float* __restrict__ bias,
                                                const float* __restrict__ resid,
                                                float* __restrict__ outf,
                                                bf16* __restrict__ outb,
                                                int N, int K) {
    __shared__ __align__(16) bf16 As[2][64 * 64];
    __shared__ __align__(16) bf16 Bs[2][64 * 64];
    int per = gridDim.x >> 3;
    int tile = (blockIdx.x & 7) * per + (blockIdx.x >> 3);
    int bm = tile & 31, bn = tile >> 5;
    int t = threadIdx.x, lane = t & 63, wid = t >> 6;
    f32x4 acc[4] = {};
    const char* Ab = (const char*)(A + (size_t)bm * 64 * K);
    const char* Bb = (const char*)(BT + (size_t)bn * 64 * K);
    int Kb = K * 2;
    int nk = K >> 6;
    stage64(Ab, Bb, (char*)As[0], (char*)Bs[0], Kb, 0, t);
    VMW(0); BARR();
    for (int tt = 0; tt < nk; ++tt) {
        int cur = tt & 1;
        if (tt + 1 < nk)
            stage64(Ab, Bb, (char*)As[cur ^ 1], (char*)Bs[cur ^ 1], Kb, (tt + 1) * 128, t);
        const char* Ac = (const char*)As[cur];
        const char* Bc = (const char*)Bs[cur];
#pragma unroll
        for (int kk = 0; kk < 2; ++kk) {
            int cb = kk * 64 + ((lane >> 4) << 4);
            int ra = wid * 16 + (lane & 15);
            bf16x8 af = *(const bf16x8*)(Ac + ra * 128 + (cb ^ ((ra & 7) << 4)));
            bf16x8 bfr[4];
#pragma unroll
            for (int n = 0; n < 4; ++n) {
                int r = n * 16 + (lane & 15);
                bfr[n] = *(const bf16x8*)(Bc + r * 128 + (cb ^ ((r & 7) << 4)));
            }
#pragma unroll
            for (int n = 0; n < 4; ++n)
                acc[n] = __builtin_amdgcn_mfma_f32_16x16x32_bf16(af, bfr[n], acc[n], 0, 0, 0);
        }
        VMW(0); BARR();
    }
    int row0 = bm * 64 + wid * 16 + ((lane >> 4) << 2);
    int col0 = bn * 64 + (lane & 15);
#pragma unroll
    for (int n = 0; n < 4; ++n) {
        int col = col0 + n * 16;
        float bv = bias[col];
#pragma unroll
        for (int r = 0; r < 4; ++r) {
            int row = row0 + r;
            size_t idx = (size_t)row * N + col;
            float v = acc[n][r] + bv;
            float res;
            if (EPI == 1) {
                res = resid[idx] + v;
            } else {
                res = resid[idx] + 0.5f * v * (1.0f + erff(v * 0.70710678118f));
            }
            outf[idx] = res;
            if (outb) outb[idx] = (bf16)res;   // fused final cast (layer 5 mlp2)
        }
    }
}

// ---------------- 256x256 GEMM (logits): phased K-loop ------------------
__device__ __forceinline__ void stage_full256(const char* gtile, char* ldst,
                                              int Kb, int t) {
#pragma unroll
    for (int j = 0; j < 4; ++j) {
        int idx = j * 512 + t;
        int row = idx >> 3;
        int cb = (idx & 7) << 4;
        int scb = cb ^ ((row & 7) << 4);
        gld_lds16(gtile + (size_t)row * Kb + scb, ldst + idx * 16);
    }
}

__device__ __forceinline__ void stage_half256(const char* gtile, char* ldst,
                                              int Kb, int t, int half) {
#pragma unroll
    for (int j = 0; j < 2; ++j) {
        int idx = (half * 2 + j) * 512 + t;
        int row = idx >> 3;
        int cb = (idx & 7) << 4;
        int scb = cb ^ ((row & 7) << 4);
        gld_lds16(gtile + (size_t)row * Kb + scb, ldst + idx * 16);
    }
}

template <int MH, int NH>
__device__ __forceinline__ void phase_rd(const char* Ac, const char* Bc,
                                         int lrow, int lk, int wm, int wn,
                                         bf16x8 (&af)[4][2], bf16x8 (&bfr)[2][2]) {
#pragma unroll
    for (int kk = 0; kk < 2; ++kk) {
        int cb = kk * 64 + lk * 16;
#pragma unroll
        for (int m = 0; m < 4; ++m) {
            int row = (MH * 4 + m) * 32 + wm * 16 + lrow;
            af[m][kk] = *(const bf16x8*)(Ac + row * 128 + (cb ^ ((row & 7) << 4)));
        }
#pragma unroll
        for (int n = 0; n < 2; ++n) {
            int row = (NH * 2 + n) * 64 + wn * 16 + lrow;
            bfr[n][kk] = *(const bf16x8*)(Bc + row * 128 + (cb ^ ((row & 7) << 4)));
        }
    }
}

template <int MH, int NH>
__device__ __forceinline__ void phase_mm(bf16x8 (&af)[4][2], bf16x8 (&bfr)[2][2],
                                         f32x4 (&acc)[8][4]) {
    __builtin_amdgcn_s_setprio(1);
#pragma unroll
    for (int kk = 0; kk < 2; ++kk)
#pragma unroll
        for (int m = 0; m < 4; ++m)
#pragma unroll
            for (int n = 0; n < 2; ++n)
                acc[MH * 4 + m][NH * 2 + n] = __builtin_amdgcn_mfma_f32_16x16x32_bf16(
                    af[m][kk], bfr[n][kk], acc[MH * 4 + m][NH * 2 + n], 0, 0, 0);
    __builtin_amdgcn_s_setprio(0);
    __builtin_amdgcn_sched_barrier(0);
}

__global__ __launch_bounds__(512, 1) void k_gemm256(const bf16* __restrict__ A,
                                                    const bf16* __restrict__ BT,
                                                    float* __restrict__ outf,
                                                    int N, int K) {
    __shared__ __align__(16) bf16 Asb[2][256 * 64];
    __shared__ __align__(16) bf16 Bsb[3][256 * 64];
    int t = threadIdx.x, lane = t & 63, wid = t >> 6;
    int wm = wid >> 2, wn = wid & 3;
    int lrow = lane & 15, lk = lane >> 4;
    int tile = (blockIdx.x & 7) * 125 + (blockIdx.x >> 3);
    int bm = tile & 7;
    int bn = tile >> 3;

    const char* Ab = (const char*)(A + (size_t)bm * 256 * K);
    const char* Bb = (const char*)(BT + (size_t)bn * 256 * K);
    int Kb = K * 2;
    int nk = K >> 6;
    f32x4 acc[8][4] = {};

    stage_full256(Ab, (char*)Asb[0], Kb, t);
    stage_full256(Bb, (char*)Bsb[0], Kb, t);
    stage_full256(Bb + 128, (char*)Bsb[1], Kb, t);

    for (int tt = 0; tt < nk; ++tt) {
        int ka = (tt + 1 < nk) ? tt + 1 : nk - 1;
        int kb = (tt + 2 < nk) ? tt + 2 : nk - 1;
        const char* Ac = (const char*)Asb[tt & 1];
        const char* Bc = (const char*)Bsb[tt % 3];
        char* An = (char*)Asb[(tt + 1) & 1];
        char* Bn = (char*)Bsb[(tt + 2) % 3];
        const char* Ag = Ab + (size_t)ka * 128;
        const char* Bg = Bb + (size_t)kb * 128;
        VMW(4); BARR();
        bf16x8 af[4][2], bfr[2][2];
        phase_rd<0, 0>(Ac, Bc, lrow, lk, wm, wn, af, bfr);
        stage_half256(Ag, An, Kb, t, 0);
        BARR();
        phase_mm<0, 0>(af, bfr, acc);
        BARR();
        phase_rd<0, 1>(Ac, Bc, lrow, lk, wm, wn, af, bfr);
        stage_half256(Ag, An, Kb, t, 1);
        BARR();
        phase_mm<0, 1>(af, bfr, acc);
        BARR();
        phase_rd<1, 0>(Ac, Bc, lrow, lk, wm, wn, af, bfr);
        stage_half256(Bg, Bn, Kb, t, 0);
        BARR();
        phase_mm<1, 0>(af, bfr, acc);
        BARR();
        phase_rd<1, 1>(Ac, Bc, lrow, lk, wm, wn, af, bfr);
        stage_half256(Bg, Bn, Kb, t, 1);
        BARR();
        phase_mm<1, 1>(af, bfr, acc);
        BARR();
    }

    size_t row0 = (size_t)bm * 256 + wm * 16 + (lane >> 4) * 4;
    int col0 = bn * 256 + wn * 16 + (lane & 15);
#pragma unroll
    for (int mi = 0; mi < 8; ++mi) {
#pragma unroll
        for (int ni = 0; ni < 4; ++ni) {
            int col = col0 + ni * 64;
#pragma unroll
            for (int r = 0; r < 4; ++r) {
                size_t row = row0 + mi * 32 + r;
                outf[row * N + col] = acc[mi][ni][r];
            }
        }
    }
}

// ---------------- heterogeneous: flash attention + weight transpose ----------------
// Attn blocks [0,256): each handles TWO complementary q-blocks (qbp, 15-qbp)
// serially -> constant 17 kv-tiles per block (causal-work balancing; previously
// the worst CU carried ~31 tile-units). K/V double-buffered with T14 prefetch.
// Blocks >=256: next-layer weight transpose or out_w transpose.
__global__ __launch_bounds__(256) void k_attn_tr(const bf16* __restrict__ qkv,
                                                 bf16* __restrict__ y,
                                                 const float* __restrict__ aw,
                                                 const float* __restrict__ pw,
                                                 const float* __restrict__ m1,
                                                 const float* __restrict__ m2,
                                                 bf16* __restrict__ wTnext,
                                                 const float* __restrict__ outw,
                                                 bf16* __restrict__ outT) {
    __shared__ __align__(16) char smem[49152];
    int bidg = blockIdx.x;
    int t = threadIdx.x;
    if (bidg >= 256) {
        int tb = bidg - 256;
        float (*tile)[65] = (float(*)[65])smem;
        if (aw) {
            tr_layer_block(tb, aw, pw, m1, m2, wTnext, t, tile);
        } else {
            int tn = tb % 500, tk = tb / 500;
            transpose64(outw, outT, 1024, 32000, tn * 64, tk * 64, t, tile);
        }
        return;
    }
    bf16* Qs  = (bf16*)smem;
    bf16* KsA = Qs + 4096;
    bf16* KsB = KsA + 4096;
    bf16* VtA = KsB + 4096;
    bf16* VtB = VtA + 4096;
    bf16* Ps  = VtB + 4096;
    // 256 attn blocks = 8 q-pairs x 32 bh, XCD-grouped (bh contiguous per XCD)
    int tile = (bidg & 7) * 32 + (bidg >> 3);
    int qbp = tile & 7;
    int bh = tile >> 3;
    int b = bh >> 4, h = bh & 15;
    int lane = t & 63, wid = t >> 6;
    int lr = lane & 15, lk = lane >> 4;
    int tok0 = b << 10;
    const char* qbase = (const char*)qkv;
    int kvr = t >> 2, d0v = (t & 3) * 16;

    auto stageK = [&](int kv0, bf16* Kb) {
#pragma unroll
        for (int j = 0; j < 2; ++j) {
            int off = (j * 256 + t) * 16;
            int row = off >> 7, colb = off & 127;
            int scb = colb ^ ((row & 7) << 4);
            gld_lds16(qbase + ((size_t)(tok0 + kv0 + row) * 3072 + 1024 + h * 64) * 2 + scb,
                      (char*)Kb + off);
        }
    };
    bf16x4 vreg[4];
    auto loadV = [&](int kv0) {
        const bf16* vrow = qkv + (size_t)(tok0 + kv0 + kvr) * 3072 + 2048 + h * 64 + d0v;
#pragma unroll
        for (int e4 = 0; e4 < 4; ++e4) vreg[e4] = *(const bf16x4*)(vrow + e4 * 4);
    };
    auto writeV = [&](bf16* Vb) {
#pragma unroll
        for (int e4 = 0; e4 < 4; ++e4)
#pragma unroll
            for (int i2 = 0; i2 < 4; ++i2) {
                int d = d0v + e4 * 4 + i2;
                Vb[d * 64 + (kvr ^ ((d & 7) << 3))] = vreg[e4][i2];
            }
    };

    for (int ph = 0; ph < 2; ++ph) {
        int qb = ph ? (15 - qbp) : qbp;
        int q0 = qb << 6;
        // prologue: stage Q + K(0) (gld_lds) and V(0) (regs) concurrently
#pragma unroll
        for (int j = 0; j < 2; ++j) {
            int off = (j * 256 + t) * 16;
            int row = off >> 7, colb = off & 127;
            int scb = colb ^ ((row & 7) << 4);
            gld_lds16(qbase + ((size_t)(tok0 + q0 + row) * 3072 + h * 64) * 2 + scb,
                      (char*)Qs + off);
        }
        stageK(0, KsA);
        loadV(0);
        VMW(0);
        writeV(VtA);
        __syncthreads();

        int qrw = wid * 16 + lr;
        int qsw = (qrw & 7) << 4;
        bf16x8 aq0 = *(const bf16x8*)((const char*)Qs + qrw * 128 + ((lk * 16) ^ qsw));
        bf16x8 aq1 = *(const bf16x8*)((const char*)Qs + qrw * 128 + ((64 + lk * 16) ^ qsw));
        f32x4 o[4] = {};
        float mrun[4], lrun[4];
#pragma unroll
        for (int r = 0; r < 4; ++r) { mrun[r] = -INFINITY; lrun[r] = 0.f; }
        int qrow = q0 + wid * 16 + lk * 4;
        int nt = qb + 1;

        for (int ti = 0; ti < nt; ++ti) {
            int kv0 = ti << 6;
            bf16* Kc = (ti & 1) ? KsB : KsA;
            bf16* Vc = (ti & 1) ? VtB : VtA;
            bf16* Kn = (ti & 1) ? KsA : KsB;
            bf16* Vn = (ti & 1) ? VtA : VtB;
            bool pf = (ti + 1 < nt);
            if (pf) { stageK((ti + 1) << 6, Kn); loadV((ti + 1) << 6); }
            f32x4 s[4];
#pragma unroll
            for (int n = 0; n < 4; ++n) {
                int krw = n * 16 + lr;
                int ksw = (krw & 7) << 4;
                const char* kb = (const char*)Kc + krw * 128;
                bf16x8 bk0 = *(const bf16x8*)(kb + ((lk * 16) ^ ksw));
                bf16x8 bk1 = *(const bf16x8*)(kb + ((64 + lk * 16) ^ ksw));
                f32x4 z = {};
                z = __builtin_amdgcn_mfma_f32_16x16x32_bf16(aq0, bk0, z, 0, 0, 0);
                z = __builtin_amdgcn_mfma_f32_16x16x32_bf16(aq1, bk1, z, 0, 0, 0);
                s[n] = z;
            }
            float mx[4];
#pragma unroll
            for (int r = 0; r < 4; ++r) mx[r] = -INFINITY;
#pragma unroll
            for (int n = 0; n < 4; ++n) {
                int col = kv0 + n * 16 + lr;
#pragma unroll
                for (int r = 0; r < 4; ++r) {
                    float sv = s[n][r] * 0.125f;
                    sv = (col <= qrow + r) ? sv : -INFINITY;
                    s[n][r] = sv;
                    mx[r] = fmaxf(mx[r], sv);
                }
            }
#pragma unroll
            for (int r = 0; r < 4; ++r)
#pragma unroll
                for (int m = 1; m < 16; m <<= 1) mx[r] = fmaxf(mx[r], __shfl_xor(mx[r], m));
            float scl[4];
#pragma unroll
            for (int r = 0; r < 4; ++r) {
                float mn = fmaxf(mrun[r], mx[r]);
                scl[r] = __expf(mrun[r] - mn);
                mrun[r] = mn;
            }
            float rs[4] = {0.f, 0.f, 0.f, 0.f};
#pragma unroll
            for (int n = 0; n < 4; ++n)
#pragma unroll
                for (int r = 0; r < 4; ++r) {
                    float p = __expf(s[n][r] - mrun[r]);
                    s[n][r] = p;
                    rs[r] += p;
                }
#pragma unroll
            for (int r = 0; r < 4; ++r) {
#pragma unroll
                for (int m = 1; m < 16; m <<= 1) rs[r] += __shfl_xor(rs[r], m);
                lrun[r] = lrun[r] * scl[r] + rs[r];
            }
#pragma unroll
            for (int n = 0; n < 4; ++n)
#pragma unroll
                for (int r = 0; r < 4; ++r) {
                    o[n][r] *= scl[r];
                    int prow = lk * 4 + r;
                    Ps[wid * 1024 + prow * 64 + ((n * 16 + lr) ^ ((prow & 7) << 3))] = (bf16)s[n][r];
                }
            int psw = (lr & 7) << 3;
            const bf16* pb = Ps + wid * 1024 + lr * 64;
            bf16x8 ap0 = *(const bf16x8*)(pb + ((lk * 8) ^ psw));
            bf16x8 ap1 = *(const bf16x8*)(pb + ((32 + lk * 8) ^ psw));
#pragma unroll
            for (int n = 0; n < 4; ++n) {
                int vrw = n * 16 + lr;
                int vsw = (vrw & 7) << 3;
                const bf16* vb = Vc + vrw * 64;
                bf16x8 bv0 = *(const bf16x8*)(vb + ((lk * 8) ^ vsw));
                bf16x8 bv1 = *(const bf16x8*)(vb + ((32 + lk * 8) ^ vsw));
                o[n] = __builtin_amdgcn_mfma_f32_16x16x32_bf16(ap0, bv0, o[n], 0, 0, 0);
                o[n] = __builtin_amdgcn_mfma_f32_16x16x32_bf16(ap1, bv1, o[n], 0, 0, 0);
            }
            if (pf) { VMW(0); writeV(Vn); }
            __syncthreads();
        }
#pragma unroll
        for (int n = 0; n < 4; ++n)
#pragma unroll
            for (int r = 0; r < 4; ++r) {
                int row = tok0 + qrow + r;
                y[(size_t)row * 1024 + h * 64 + n * 16 + lr] = (bf16)(o[n][r] / lrun[r]);
            }
    }
}

extern "C" void kernel_launch(void* const* d_in, const int* in_sizes, int n_in,
                              void* d_out, int out_size, void* d_ws, size_t ws_size,
                              hipStream_t stream) {
    const int*   tokens = (const int*)d_in[0];
    const float* pos    = (const float*)d_in[1];
    const float* emb    = (const float*)d_in[2];
    const float* ln1_g  = (const float*)d_in[3];
    const float* ln1_b  = (const float*)d_in[4];
    const float* ln2_g  = (const float*)d_in[5];
    const float* ln2_b  = (const float*)d_in[6];
    const float* attn_w = (const float*)d_in[7];
    const float* attn_b = (const float*)d_in[8];
    const float* proj_w = (const float*)d_in[9];
    const float* proj_b = (const float*)d_in[10];
    const float* mlp_w1 = (const float*)d_in[11];
    const float* mlp_b1 = (const float*)d_in[12];
    const float* mlp_w2 = (const float*)d_in[13];
    const float* mlp_b2 = (const float*)d_in[14];
    const float* out_w  = (const float*)d_in[15];
    float* out = (float*)d_out;

    char* ws = (char*)d_ws;
    size_t off = 0;
    auto alloc = [&](size_t bytes) {
        void* p = ws + off;
        off = (off + bytes + 255) & ~(size_t)255;
        return p;
    };
    float* x   = (float*)alloc((size_t)2048 * 1024 * 4);
    bf16* hb   = (bf16*)alloc((size_t)2048 * 1024 * 2);
    bf16* qkvb = (bf16*)alloc((size_t)2048 * 3072 * 2);
    bf16* yb   = (bf16*)alloc((size_t)2048 * 1024 * 2);
    bf16* hidb = (bf16*)alloc((size_t)2048 * 4096 * 2);
    // outT (32000x1024) doubles as wT slot0 in its first 9437184 elements:
    // slot0's last read (layer-4 mlp2) precedes outT's write (layer-5 attn launch).
    bf16* outT = (bf16*)alloc((size_t)32000 * 1024 * 2);
    bf16* slot1 = (bf16*)alloc((size_t)9437184 * 2);
    bf16* slots[2] = { outT, slot1 };

    k_embed<<<2048, 256, 0, stream>>>(tokens, emb, pos, x);
    k_transpose_layer<<<3072, 256, 0, stream>>>(attn_w, proj_w, mlp_w1, mlp_w2, slots[0]);

    for (int i = 0; i < 6; ++i) {
        bf16* wT = slots[i & 1];
        k_ln<<<2048, 256, 0, stream>>>(x, ln1_g + i * 1024, ln1_b + i * 1024, hb);
        k_gemm2<0><<<384, 256, 0, stream>>>(hb, wT, attn_b + i * 3072,
                                            nullptr, nullptr, qkvb, 3072, 1024);
        if (i < 5) {
            int j = i + 1;
            k_attn_tr<<<3328, 256, 0, stream>>>(qkvb, yb,
                attn_w + (size_t)j * 1024 * 3072, proj_w + (size_t)j * 1024 * 1024,
                mlp_w1 + (size_t)j * 1024 * 4096, mlp_w2 + (size_t)j * 4096 * 1024,
                slots[j & 1], nullptr, nullptr);
        } else {
            k_attn_tr<<<8256, 256, 0, stream>>>(qkvb, yb,
                nullptr, nullptr, nullptr, nullptr, nullptr, out_w, outT);
        }
        k_gemm64<1><<<512, 256, 0, stream>>>(yb, wT + 3145728, proj_b + i * 1024,
                                             x, x, nullptr, 1024, 1024);
        k_ln<<<2048, 256, 0, stream>>>(x, ln2_g + i * 1024, ln2_b + i * 1024, hb);
        k_gemm2<0><<<512, 256, 0, stream>>>(hb, wT + 4194304, mlp_b1 + i * 4096,
                                            nullptr, nullptr, hidb, 4096, 1024);
        k_gemm64<2><<<512, 256, 0, stream>>>(hidb, wT + 8388608, mlp_b2 + i * 1024,
                                             x, x, (i == 5) ? hb : nullptr, 1024, 4096);
    }

    k_gemm256<<<1000, 512, 0, stream>>>(hb, outT, out, 32000, 1024);
}